// Round 22
// baseline (155.372 us; speedup 1.0000x reference)
//
#include <hip/hip_runtime.h>
#include <hip/hip_bf16.h>

#define HW_N 9216
#define CH 256
#define KBLK 32                          // keys per loop iteration (2 keyblocks of 16)
#define SCALE2 144.269504089f            // 100 / ln(2), folded into xn at normalize time
#define INV_SCALE2 6.93147180559945e-3f  // ln(2) / 100

typedef __attribute__((ext_vector_type(8))) short bf16x8;
typedef __attribute__((ext_vector_type(4))) float f32x4;

__device__ inline unsigned short f2b(float f) {
    unsigned u = __builtin_bit_cast(unsigned, f);
    u += 0x7FFF + ((u >> 16) & 1);       // round-to-nearest-even
    return (unsigned short)(u >> 16);
}

// raw v_exp_f32 (libm exp2f = guarded multi-instr sequence; args bounded)
__device__ inline float fexp2(float x) {
    float r; asm("v_exp_f32 %0, %1" : "=v"(r) : "v"(x)); return r;
}

// ---------------- kernel 1: per-channel partial sums (R20 proven) ------------------
__global__ void stats_partial(const float* __restrict__ x,
                              const float* __restrict__ y,
                              float* __restrict__ part) {
    int c = threadIdx.x;                  // 256 threads = 256 channels
    int r0 = blockIdx.x * 128;            // 72 blocks * 128 rows = 9216
    float xs = 0.f, xq = 0.f, ys = 0.f, yq = 0.f;
    for (int r = r0; r < r0 + 128; ++r) {
        float xv = x[(size_t)r * CH + c]; xs += xv; xq += xv * xv;
        float yv = y[(size_t)r * CH + c]; ys += yv; yq += yv * yv;
    }
    float* p = part + (size_t)blockIdx.x * 1024;
    p[c] = xs; p[256 + c] = xq; p[512 + c] = ys; p[768 + c] = yq;
}

// ---------------- kernel 2: finalize stats (x-side invnorm pre-scaled) -------------
__global__ void stats_final(const float* __restrict__ part, float* __restrict__ stats) {
    int c = threadIdx.x;
    float xs = 0.f, xq = 0.f, ys = 0.f, yq = 0.f;
    for (int b = 0; b < 72; ++b) {
        const float* p = part + (size_t)b * 1024;
        xs += p[c]; xq += p[256 + c]; ys += p[512 + c]; yq += p[768 + c];
    }
    stats[c]       = xs / (float)HW_N;
    stats[256 + c] = SCALE2 / sqrtf(xq);  // fold logit scale into xn
    stats[512 + c] = ys / (float)HW_N;
    stats[768 + c] = 1.0f / sqrtf(yq);
}

// ---------------- kernel 3: normalize f32 -> bf16; y goes to PACKED layout ---------
__global__ void normalize_k(const float* __restrict__ x,
                            const float* __restrict__ y,
                            const float* __restrict__ stats,
                            unsigned short* __restrict__ xn,
                            unsigned short* __restrict__ ynP) {
    int idx = (blockIdx.x * 256 + threadIdx.x) * 8;   // grid.x = 1152
    int c = idx & (CH - 1);
    const float* src = blockIdx.y ? y : x;
    const float* st = stats + blockIdx.y * 512;
    float4 v0 = *(const float4*)(src + idx);
    float4 v1 = *(const float4*)(src + idx + 4);
    float f[8] = {v0.x, v0.y, v0.z, v0.w, v1.x, v1.y, v1.z, v1.w};
    bf16x8 o;
#pragma unroll
    for (int j = 0; j < 8; ++j)
        o[j] = (short)f2b((f[j] - st[c + j]) * st[256 + c + j]);
    if (blockIdx.y == 0) {
        *(bf16x8*)(xn + idx) = o;                     // row-major for A-fragments
    } else {
        int key = idx >> 8;
        int dst = (key >> 4) * 4096 + (c >> 5) * 512 + ((c & 31) >> 3) * 128 + (key & 15) * 8;
        *(bf16x8*)(ynP + dst) = o;                    // packed B-fragment layout
    }
}

// ---------------- T15-lite tile step: MFMA(cur) ∥ loads(next) ∥ softmax(prev) ------
// One wave keeps both pipes busy via program-order interleave: per kk-step,
// 4 MFMAs (matrix pipe) + 2 loads (VMEM) + one softmax q-group of the PREVIOUS
// tile's acc (VALU/trans - no dep on current MFMAs). R14 proved the numerics of
// this deferred-softmax; R17 proved the in-place b-overwrite. Combined here with
// only +16 VGPR (second acc set) - R14's spill came from its 4 B-buffer sets.
template<bool DOSM, bool DOLOAD>
__device__ __forceinline__ void tile_step(
    const bf16x8 (&a)[2][8], bf16x8 (&b0)[8], bf16x8 (&b1)[8],
    f32x4 (&C0)[2], f32x4 (&C1)[2],
    const f32x4 (&P0)[2], const f32x4 (&P1)[2],
    float pva0, float pva1, float pvb0, float pvb1,
    const char* segn,
    float (&M)[2][4], float (&den)[2][4], float (&nA)[2][4], float (&nB)[2][4])
{
    C0[0] = (f32x4){0.f,0.f,0.f,0.f}; C0[1] = (f32x4){0.f,0.f,0.f,0.f};
    C1[0] = (f32x4){0.f,0.f,0.f,0.f}; C1[1] = (f32x4){0.f,0.f,0.f,0.f};
#pragma unroll
    for (int kk = 0; kk < 8; ++kk) {
        C0[0] = __builtin_amdgcn_mfma_f32_16x16x32_bf16(a[0][kk], b0[kk], C0[0], 0, 0, 0);
        C1[0] = __builtin_amdgcn_mfma_f32_16x16x32_bf16(a[1][kk], b0[kk], C1[0], 0, 0, 0);
        C0[1] = __builtin_amdgcn_mfma_f32_16x16x32_bf16(a[0][kk], b1[kk], C0[1], 0, 0, 0);
        C1[1] = __builtin_amdgcn_mfma_f32_16x16x32_bf16(a[1][kk], b1[kk], C1[1], 0, 0, 0);
        if constexpr (DOLOAD) {
            // b[kk] dead after its 4 MFMAs: overwrite with next tile's data
            b0[kk] = *(const bf16x8*)(segn + kk * 1024);
            b1[kk] = *(const bf16x8*)(segn + 8192 + kk * 1024);
        }
        if constexpr (DOSM) {
            const int qs = kk >> 2, i = kk & 3;       // 8 kk-steps = 8 softmax groups
            float c0 = qs ? P1[0][i] : P0[0][i];
            float c1 = qs ? P1[1][i] : P0[1][i];
            M[qs][i] = fmaxf(fmaxf(M[qs][i], c0), c1);
            float p0 = fexp2(c0), p1 = fexp2(c1);
            den[qs][i] += p0 + p1;
            nA[qs][i] += p0 * pva0 + p1 * pva1;
            nB[qs][i] += p0 * pvb0 + p1 * pvb1;
        }
    }
}

__device__ __forceinline__ void softmax_tile(
    const f32x4 (&P0)[2], const f32x4 (&P1)[2],
    float va0, float va1, float vb0, float vb1,
    float (&M)[2][4], float (&den)[2][4], float (&nA)[2][4], float (&nB)[2][4])
{
#pragma unroll
    for (int qs = 0; qs < 2; ++qs)
#pragma unroll
        for (int i = 0; i < 4; ++i) {
            float c0 = qs ? P1[0][i] : P0[0][i];
            float c1 = qs ? P1[1][i] : P0[1][i];
            M[qs][i] = fmaxf(fmaxf(M[qs][i], c0), c1);
            float p0 = fexp2(c0), p1 = fexp2(c1);
            den[qs][i] += p0 + p1;
            nA[qs][i] += p0 * va0 + p1 * va1;
            nB[qs][i] += p0 * vb0 + p1 * vb1;
        }
}

// ---------------- kernel 4: fused corr -> softmax -> PV: in-wave dual-pipe ---------
// 72*nsplit blocks (XCD swizzle), 256 thr = 4 waves, wave owns 32 q-rows.
__launch_bounds__(256, 2)
__global__ void attn_k(const unsigned short* __restrict__ xn,
                       const unsigned short* __restrict__ ynP,
                       const float* __restrict__ refimg,
                       float* __restrict__ part, int nsplit) {
    int tid = threadIdx.x;
    int lane = tid & 63, wave = tid >> 6;
    int l15 = lane & 15, l16 = lane >> 4;

    // XCD-chunked bijective swizzle (grid % 8 == 0)
    int chunk = gridDim.x >> 3;
    int wg = (blockIdx.x & 7) * chunk + (blockIdx.x >> 3);
    int bx = wg % 72, by = wg / 72;
    int qb = bx * 128 + wave * 32;
    int keys_per_split = HW_N / nsplit;
    int key0 = by * keys_per_split;
    int ntile = keys_per_split / KBLK;                // 24 or 48 (even)
    int phase = (wg * 5) % ntile;                     // block-uniform stagger (proven text)

    // A fragments (xn pre-scaled by SCALE2): q = qb + qs*16 + l15, k = kk*32 + l16*8 + j
    bf16x8 a[2][8];
#pragma unroll
    for (int qs = 0; qs < 2; ++qs) {
        const unsigned short* xrow = xn + (size_t)(qb + qs * 16 + l15) * CH + l16 * 8;
#pragma unroll
        for (int kk = 0; kk < 8; ++kk) a[qs][kk] = *(const bf16x8*)(xrow + kk * 32);
    }

    float M[2][4], den[2][4], nA[2][4], nB[2][4];
#pragma unroll
    for (int qs = 0; qs < 2; ++qs)
#pragma unroll
        for (int i = 0; i < 4; ++i) {
            M[qs][i] = -1e30f; den[qs][i] = 0.f; nA[qs][i] = 0.f; nB[qs][i] = 0.f;
        }

    const float* refA = refimg + HW_N;
    const float* refB = refimg + 2 * HW_N;
    const char* segbase = (const char*)ynP + ((size_t)(key0 >> 4) << 13) + lane * 16;

    bf16x8 b0[8], b1[8];
    f32x4 A0[2], A1[2], Bc0[2], Bc1[2];               // two acc sets (even/odd steps)
    float eva0, evb0, eva1, evb1;                     // colors, even-step tiles
    float ova0, ovb0, ova1, ovb1;                     // colors, odd-step tiles

    // prologue: load b(T0) + colors(T0)
    int tc = phase;
    {
        const char* seg = segbase + ((size_t)tc << 14);
#pragma unroll
        for (int kk = 0; kk < 8; ++kk) {
            b0[kk] = *(const bf16x8*)(seg + kk * 1024);
            b1[kk] = *(const bf16x8*)(seg + 8192 + kk * 1024);
        }
        int kb = key0 + tc * KBLK;
        eva0 = refA[kb + l15];      evb0 = refB[kb + l15];
        eva1 = refA[kb + 16 + l15]; evb1 = refB[kb + 16 + l15];
    }

    // step 0 (even): MFMA T0 -> A; load b <- T1; no softmax yet
    int tn = tc + 1; if (tn == ntile) tn = 0;
    tile_step<false, true>(a, b0, b1, A0, A1, A0, A1, 0.f, 0.f, 0.f, 0.f,
                           segbase + ((size_t)tn << 14), M, den, nA, nB);
    { int kb = key0 + tn * KBLK;
      ova0 = refA[kb + l15];      ovb0 = refB[kb + l15];
      ova1 = refA[kb + 16 + l15]; ovb1 = refB[kb + 16 + l15]; }
    tc = tn;

    // pairs of steps (odd, even); (ntile-2)/2 iterations
    for (int p = 0; p < (ntile - 2) / 2; ++p) {
        // odd step: MFMA T(tc) -> B, softmax(A, colE); prefetch next
        tn = tc + 1; if (tn == ntile) tn = 0;
        tile_step<true, true>(a, b0, b1, Bc0, Bc1, A0, A1,
                              eva0, eva1, evb0, evb1,
                              segbase + ((size_t)tn << 14), M, den, nA, nB);
        { int kb = key0 + tn * KBLK;
          eva0 = refA[kb + l15];      evb0 = refB[kb + l15];
          eva1 = refA[kb + 16 + l15]; evb1 = refB[kb + 16 + l15]; }
        tc = tn;
        // even step: MFMA T(tc) -> A, softmax(B, colO); prefetch next
        tn = tc + 1; if (tn == ntile) tn = 0;
        tile_step<true, true>(a, b0, b1, A0, A1, Bc0, Bc1,
                              ova0, ova1, ovb0, ovb1,
                              segbase + ((size_t)tn << 14), M, den, nA, nB);
        { int kb = key0 + tn * KBLK;
          ova0 = refA[kb + l15];      ovb0 = refB[kb + l15];
          ova1 = refA[kb + 16 + l15]; ovb1 = refB[kb + 16 + l15]; }
        tc = tn;
    }

    // final odd step: MFMA T(last) -> B, softmax(A, colE); no load
    tile_step<true, false>(a, b0, b1, Bc0, Bc1, A0, A1,
                           eva0, eva1, evb0, evb1, nullptr, M, den, nA, nB);
    // epilogue: softmax of the last tile (B, colO)
    softmax_tile(Bc0, Bc1, ova0, ova1, ovb0, ovb1, M, den, nA, nB);

    // merge lane-local states across the 16 column-lanes: plain sum + max
#pragma unroll
    for (int qs = 0; qs < 2; ++qs)
#pragma unroll
        for (int i = 0; i < 4; ++i) {
#pragma unroll
            for (int off = 1; off < 16; off <<= 1) {
                M[qs][i]   = fmaxf(M[qs][i], __shfl_xor(M[qs][i], off, 64));
                den[qs][i] += __shfl_xor(den[qs][i], off, 64);
                nA[qs][i]  += __shfl_xor(nA[qs][i], off, 64);
                nB[qs][i]  += __shfl_xor(nB[qs][i], off, 64);
            }
        }
    if (l15 == 0) {
#pragma unroll
        for (int qs = 0; qs < 2; ++qs)
#pragma unroll
            for (int i = 0; i < 4; ++i) {
                int q = qb + qs * 16 + l16 * 4 + i;
                float* p = part + ((size_t)by * HW_N + q) * 4;
                p[0] = M[qs][i]; p[1] = den[qs][i]; p[2] = nA[qs][i]; p[3] = nB[qs][i];
            }
    }
}

// ---------------- kernel 5: merge splits, write f32 outputs ------------------------
__global__ void combine_k(const float* __restrict__ part, float* __restrict__ out,
                          int nsplit) {
    int q = blockIdx.x * 256 + threadIdx.x;           // 36 blocks
    float M = -1e30f, den = 0.f, nA = 0.f, nB = 0.f;
    for (int s = 0; s < nsplit; ++s) {
        const float* p = part + ((size_t)s * HW_N + q) * 4;
        M = fmaxf(M, p[0]); den += p[1]; nA += p[2]; nB += p[3];
    }
    out[q]            = nA / den;            // W channel a
    out[HW_N + q]     = nB / den;            // W channel b
    out[2 * HW_N + q] = M * INV_SCALE2;      // confidence = max corr (unscale)
}

extern "C" void kernel_launch(void* const* d_in, const int* in_sizes, int n_in,
                              void* d_out, int out_size, void* d_ws, size_t ws_size,
                              hipStream_t stream) {
    (void)in_sizes; (void)n_in; (void)out_size;
    const float* x   = (const float*)d_in[0];
    const float* y   = (const float*)d_in[1];
    const float* ref = (const float*)d_in[2];
    float* out = (float*)d_out;

    char* ws = (char*)d_ws;
    unsigned short* xn  = (unsigned short*)ws;                    // 4718592 B
    unsigned short* ynP = (unsigned short*)(ws + 4718592);        // 4718592 B (packed)
    float* partA = (float*)ws;                                    // dead before xn written
    float* stats = (float*)(ws + 2 * 4718592);                    // 4096 B
    float* partS = (float*)(ws + 2 * 4718592 + 4096);             // nsplit*9216*16 B

    size_t base = 2 * 4718592 + 4096;
    int nsplit = (ws_size >= base + (size_t)12 * HW_N * 16) ? 12 : 6;

    hipLaunchKernelGGL(stats_partial, dim3(72), dim3(256), 0, stream, x, y, partA);
    hipLaunchKernelGGL(stats_final, dim3(1), dim3(256), 0, stream, partA, stats);
    hipLaunchKernelGGL(normalize_k, dim3(1152, 2), dim3(256), 0, stream, x, y, stats, xn, ynP);
    hipLaunchKernelGGL(attn_k, dim3(72 * nsplit), dim3(256), 0, stream, xn, ynP, ref, partS, nsplit);
    hipLaunchKernelGGL(combine_k, dim3(36), dim3(256), 0, stream, partS, out, nsplit);
}

// Round 23
// 88.535 us; speedup vs baseline: 1.7549x; 1.7549x over previous
//
#include <hip/hip_runtime.h>
#include <hip/hip_bf16.h>

#define HW_N 9216
#define CH 256
#define KBLK 32                          // keys per loop iteration (2 keyblocks of 16)
#define SCALE2 144.269504089f            // 100 / ln(2), folded into xn at normalize time
#define INV_SCALE2 6.93147180559945e-3f  // ln(2) / 100

typedef __attribute__((ext_vector_type(8))) short bf16x8;
typedef __attribute__((ext_vector_type(4))) float f32x4;

__device__ inline unsigned short f2b(float f) {
    unsigned u = __builtin_bit_cast(unsigned, f);
    u += 0x7FFF + ((u >> 16) & 1);       // round-to-nearest-even
    return (unsigned short)(u >> 16);
}

// raw v_exp_f32 (libm exp2f = guarded multi-instr sequence; args bounded)
__device__ inline float fexp2(float x) {
    float r; asm("v_exp_f32 %0, %1" : "=v"(r) : "v"(x)); return r;
}

// ---------------- kernel 1: per-channel partial sums (R20 proven) ------------------
__global__ void stats_partial(const float* __restrict__ x,
                              const float* __restrict__ y,
                              float* __restrict__ part) {
    int c = threadIdx.x;                  // 256 threads = 256 channels
    int r0 = blockIdx.x * 128;            // 72 blocks * 128 rows = 9216
    float xs = 0.f, xq = 0.f, ys = 0.f, yq = 0.f;
    for (int r = r0; r < r0 + 128; ++r) {
        float xv = x[(size_t)r * CH + c]; xs += xv; xq += xv * xv;
        float yv = y[(size_t)r * CH + c]; ys += yv; yq += yv * yv;
    }
    float* p = part + (size_t)blockIdx.x * 1024;
    p[c] = xs; p[256 + c] = xq; p[512 + c] = ys; p[768 + c] = yq;
}

// ---------------- kernel 2: finalize stats — 4 blocks, 1 output/thread -------------
// Same b-ascending summation order as the single-block version -> bit-identical
// stats; 4x less serial latency per thread (72 loads instead of 288).
__global__ void stats_final(const float* __restrict__ part, float* __restrict__ stats) {
    int o = blockIdx.x * 256 + threadIdx.x;           // 0..1023
    float s = 0.f;
    for (int b = 0; b < 72; ++b) s += part[(size_t)b * 1024 + o];
    float v;
    if (o < 256)      v = s / (float)HW_N;            // x mean
    else if (o < 512) v = SCALE2 / sqrtf(s);          // x invnorm (logit scale folded)
    else if (o < 768) v = s / (float)HW_N;            // y mean
    else              v = 1.0f / sqrtf(s);            // y invnorm
    stats[o] = v;
}

// ---------------- kernel 3: normalize f32 -> bf16; y goes to PACKED layout ---------
// ynP element index: keyblk*4096 + kk*512 + l16*128 + l15*8 + j
// so that in attn, lane l = l16*16+l15 reads its B-fragment as bytes
// [l*16, l*16+16) of the contiguous 1KB segment (keyblk, kk): fully coalesced.
__global__ void normalize_k(const float* __restrict__ x,
                            const float* __restrict__ y,
                            const float* __restrict__ stats,
                            unsigned short* __restrict__ xn,
                            unsigned short* __restrict__ ynP) {
    int idx = (blockIdx.x * 256 + threadIdx.x) * 8;   // grid.x = 1152
    int c = idx & (CH - 1);
    const float* src = blockIdx.y ? y : x;
    const float* st = stats + blockIdx.y * 512;
    float4 v0 = *(const float4*)(src + idx);
    float4 v1 = *(const float4*)(src + idx + 4);
    float f[8] = {v0.x, v0.y, v0.z, v0.w, v1.x, v1.y, v1.z, v1.w};
    bf16x8 o;
#pragma unroll
    for (int j = 0; j < 8; ++j)
        o[j] = (short)f2b((f[j] - st[c + j]) * st[256 + c + j]);
    if (blockIdx.y == 0) {
        *(bf16x8*)(xn + idx) = o;                     // row-major for A-fragments
    } else {
        int key = idx >> 8;
        int dst = (key >> 4) * 4096 + (c >> 5) * 512 + ((c & 31) >> 3) * 128 + (key & 15) * 8;
        *(bf16x8*)(ynP + dst) = o;                    // packed B-fragment layout
    }
}

// ---------------- kernel 4: fused corr -> softmax -> PV (R20 verbatim, best) -------
// 72*nsplit blocks (XCD swizzle), 256 thr = 4 waves, wave owns 32 q-rows.
// Verified best: interleaved next-tile loads inside the MFMA sequence (b[kk]
// overwritten after its last use), no setprio, per-lane segbase addressing,
// block-uniform stagger. Closed branches (measured): occupancy >2 blk/CU spills
// (VGPR law 256/waves_per_eu); T15 deferred-softmax spills (R14/R22); tile
// stagger + s_sleep anti-phase null; 8 acc chains null; LDS+counted-vmcnt worse.
__launch_bounds__(256, 2)
__global__ void attn_k(const unsigned short* __restrict__ xn,
                       const unsigned short* __restrict__ ynP,
                       const float* __restrict__ refimg,
                       float* __restrict__ part, int nsplit) {
    int tid = threadIdx.x;
    int lane = tid & 63, wave = tid >> 6;
    int l15 = lane & 15, l16 = lane >> 4;

    // XCD-chunked bijective swizzle (grid % 8 == 0)
    int chunk = gridDim.x >> 3;
    int wg = (blockIdx.x & 7) * chunk + (blockIdx.x >> 3);
    int bx = wg % 72, by = wg / 72;
    int qb = bx * 128 + wave * 32;
    int keys_per_split = HW_N / nsplit;
    int key0 = by * keys_per_split;
    int ntile = keys_per_split / KBLK;
    int phase = (wg * 5) % ntile;                     // block-uniform stagger (proven text)

    // A fragments (xn pre-scaled by SCALE2): q = qb + qs*16 + l15, k = kk*32 + l16*8 + j
    bf16x8 a[2][8];
#pragma unroll
    for (int qs = 0; qs < 2; ++qs) {
        const unsigned short* xrow = xn + (size_t)(qb + qs * 16 + l15) * CH + l16 * 8;
#pragma unroll
        for (int kk = 0; kk < 8; ++kk) a[qs][kk] = *(const bf16x8*)(xrow + kk * 32);
    }

    // lane-local state: plain max + raw exp sums (logits bounded, no rescale needed)
    float M[2][4], den[2][4], nA[2][4], nB[2][4];
#pragma unroll
    for (int qs = 0; qs < 2; ++qs)
#pragma unroll
        for (int i = 0; i < 4; ++i) {
            M[qs][i] = -1e30f; den[qs][i] = 0.f; nA[qs][i] = 0.f; nB[qs][i] = 0.f;
        }

    const float* refA = refimg + HW_N;
    const float* refB = refimg + 2 * HW_N;
    // per-lane base into packed layout: lane*16 bytes within each 1KB (keyblk,kk) segment
    const char* segbase = (const char*)ynP + ((size_t)(key0 >> 4) << 13) + lane * 16;

    bf16x8 b0[8], b1[8];
    float va0, vb0, va1, vb1;

    // prologue: load tile `phase`
    int tc = phase;
    {
        const char* seg = segbase + ((size_t)tc << 14);
#pragma unroll
        for (int kk = 0; kk < 8; ++kk) {
            b0[kk] = *(const bf16x8*)(seg + kk * 1024);
            b1[kk] = *(const bf16x8*)(seg + 8192 + kk * 1024);
        }
        int kb = key0 + tc * KBLK;
        va0 = refA[kb + l15];      vb0 = refB[kb + l15];
        va1 = refA[kb + 16 + l15]; vb1 = refB[kb + 16 + l15];
    }

    // main loop: ntile-1 iterations, always loading the next tile inside the MFMAs
    for (int tt = 0; tt < ntile - 1; ++tt) {
        int tn = tc + 1; if (tn == ntile) tn = 0;
        const char* segn = segbase + ((size_t)tn << 14);

        f32x4 acc0[2], acc1[2];
#pragma unroll
        for (int ct = 0; ct < 2; ++ct) {
            acc0[ct] = (f32x4){0.f, 0.f, 0.f, 0.f};
            acc1[ct] = (f32x4){0.f, 0.f, 0.f, 0.f};
        }
#pragma unroll
        for (int kk = 0; kk < 8; ++kk) {
            acc0[0] = __builtin_amdgcn_mfma_f32_16x16x32_bf16(a[0][kk], b0[kk], acc0[0], 0, 0, 0);
            acc1[0] = __builtin_amdgcn_mfma_f32_16x16x32_bf16(a[1][kk], b0[kk], acc1[0], 0, 0, 0);
            acc0[1] = __builtin_amdgcn_mfma_f32_16x16x32_bf16(a[0][kk], b1[kk], acc0[1], 0, 0, 0);
            acc1[1] = __builtin_amdgcn_mfma_f32_16x16x32_bf16(a[1][kk], b1[kk], acc1[1], 0, 0, 0);
            // b0[kk]/b1[kk] now dead for this tile: overwrite with next tile's data
            b0[kk] = *(const bf16x8*)(segn + kk * 1024);
            b1[kk] = *(const bf16x8*)(segn + 8192 + kk * 1024);
        }

        // snapshot current colors, fetch next tile's colors
        float cva0 = va0, cvb0 = vb0, cva1 = va1, cvb1 = vb1;
        {
            int kb = key0 + tn * KBLK;
            va0 = refA[kb + l15];      vb0 = refB[kb + l15];
            va1 = refA[kb + 16 + l15]; vb1 = refB[kb + 16 + l15];
        }
        tc = tn;

        // softmax covers the in-flight loads.
#pragma unroll
        for (int qs = 0; qs < 2; ++qs)
#pragma unroll
            for (int i = 0; i < 4; ++i) {
                float c0 = qs ? acc1[0][i] : acc0[0][i];
                float c1 = qs ? acc1[1][i] : acc0[1][i];
                M[qs][i] = fmaxf(fmaxf(M[qs][i], c0), c1);
                float p0 = fexp2(c0);
                float p1 = fexp2(c1);
                den[qs][i] += p0 + p1;
                nA[qs][i] += p0 * cva0 + p1 * cva1;
                nB[qs][i] += p0 * cvb0 + p1 * cvb1;
            }
    }

    // final tile: MFMA + softmax, no loads
    {
        f32x4 acc0[2], acc1[2];
#pragma unroll
        for (int ct = 0; ct < 2; ++ct) {
            acc0[ct] = (f32x4){0.f, 0.f, 0.f, 0.f};
            acc1[ct] = (f32x4){0.f, 0.f, 0.f, 0.f};
        }
#pragma unroll
        for (int kk = 0; kk < 8; ++kk) {
            acc0[0] = __builtin_amdgcn_mfma_f32_16x16x32_bf16(a[0][kk], b0[kk], acc0[0], 0, 0, 0);
            acc1[0] = __builtin_amdgcn_mfma_f32_16x16x32_bf16(a[1][kk], b0[kk], acc1[0], 0, 0, 0);
            acc0[1] = __builtin_amdgcn_mfma_f32_16x16x32_bf16(a[0][kk], b1[kk], acc0[1], 0, 0, 0);
            acc1[1] = __builtin_amdgcn_mfma_f32_16x16x32_bf16(a[1][kk], b1[kk], acc1[1], 0, 0, 0);
        }
#pragma unroll
        for (int qs = 0; qs < 2; ++qs)
#pragma unroll
            for (int i = 0; i < 4; ++i) {
                float c0 = qs ? acc1[0][i] : acc0[0][i];
                float c1 = qs ? acc1[1][i] : acc0[1][i];
                M[qs][i] = fmaxf(fmaxf(M[qs][i], c0), c1);
                float p0 = fexp2(c0);
                float p1 = fexp2(c1);
                den[qs][i] += p0 + p1;
                nA[qs][i] += p0 * va0 + p1 * va1;
                nB[qs][i] += p0 * vb0 + p1 * vb1;
            }
    }

    // merge lane-local states across the 16 column-lanes: plain sum + max
#pragma unroll
    for (int qs = 0; qs < 2; ++qs)
#pragma unroll
        for (int i = 0; i < 4; ++i) {
#pragma unroll
            for (int off = 1; off < 16; off <<= 1) {
                M[qs][i]   = fmaxf(M[qs][i], __shfl_xor(M[qs][i], off, 64));
                den[qs][i] += __shfl_xor(den[qs][i], off, 64);
                nA[qs][i]  += __shfl_xor(nA[qs][i], off, 64);
                nB[qs][i]  += __shfl_xor(nB[qs][i], off, 64);
            }
        }
    if (l15 == 0) {
#pragma unroll
        for (int qs = 0; qs < 2; ++qs)
#pragma unroll
            for (int i = 0; i < 4; ++i) {
                int q = qb + qs * 16 + l16 * 4 + i;
                float* p = part + ((size_t)by * HW_N + q) * 4;
                p[0] = M[qs][i]; p[1] = den[qs][i]; p[2] = nA[qs][i]; p[3] = nB[qs][i];
            }
    }
}

// ---------------- kernel 5: merge splits, write f32 outputs ------------------------
__global__ void combine_k(const float* __restrict__ part, float* __restrict__ out,
                          int nsplit) {
    int q = blockIdx.x * 256 + threadIdx.x;           // 36 blocks
    float M = -1e30f, den = 0.f, nA = 0.f, nB = 0.f;
    for (int s = 0; s < nsplit; ++s) {
        const float* p = part + ((size_t)s * HW_N + q) * 4;
        M = fmaxf(M, p[0]); den += p[1]; nA += p[2]; nB += p[3];
    }
    out[q]            = nA / den;            // W channel a
    out[HW_N + q]     = nB / den;            // W channel b
    out[2 * HW_N + q] = M * INV_SCALE2;      // confidence = max corr (unscale)
}

extern "C" void kernel_launch(void* const* d_in, const int* in_sizes, int n_in,
                              void* d_out, int out_size, void* d_ws, size_t ws_size,
                              hipStream_t stream) {
    (void)in_sizes; (void)n_in; (void)out_size;
    const float* x   = (const float*)d_in[0];
    const float* y   = (const float*)d_in[1];
    const float* ref = (const float*)d_in[2];
    float* out = (float*)d_out;

    char* ws = (char*)d_ws;
    unsigned short* xn  = (unsigned short*)ws;                    // 4718592 B
    unsigned short* ynP = (unsigned short*)(ws + 4718592);        // 4718592 B (packed)
    float* partA = (float*)ws;                                    // dead before xn written
    float* stats = (float*)(ws + 2 * 4718592);                    // 4096 B
    float* partS = (float*)(ws + 2 * 4718592 + 4096);             // nsplit*9216*16 B

    size_t base = 2 * 4718592 + 4096;
    int nsplit = (ws_size >= base + (size_t)12 * HW_N * 16) ? 12 : 6;

    hipLaunchKernelGGL(stats_partial, dim3(72), dim3(256), 0, stream, x, y, partA);
    hipLaunchKernelGGL(stats_final, dim3(4), dim3(256), 0, stream, partA, stats);
    hipLaunchKernelGGL(normalize_k, dim3(1152, 2), dim3(256), 0, stream, x, y, stats, xn, ynP);
    hipLaunchKernelGGL(attn_k, dim3(72 * nsplit), dim3(256), 0, stream, xn, ynP, ref, partS, nsplit);
    hipLaunchKernelGGL(combine_k, dim3(36), dim3(256), 0, stream, partS, out, nsplit);
}

// Round 24
// 87.189 us; speedup vs baseline: 1.7820x; 1.0154x over previous
//
#include <hip/hip_runtime.h>
#include <hip/hip_bf16.h>

#define HW_N 9216
#define CH 256
#define KBLK 32                          // keys per loop iteration (2 keyblocks of 16)
#define SCALE2 144.269504089f            // 100 / ln(2), folded into xn at normalize time
#define INV_SCALE2 6.93147180559945e-3f  // ln(2) / 100

typedef __attribute__((ext_vector_type(8))) short bf16x8;
typedef __attribute__((ext_vector_type(4))) float f32x4;

__device__ inline unsigned short f2b(float f) {
    unsigned u = __builtin_bit_cast(unsigned, f);
    u += 0x7FFF + ((u >> 16) & 1);       // round-to-nearest-even
    return (unsigned short)(u >> 16);
}

// raw v_exp_f32 (libm exp2f = guarded multi-instr sequence; args bounded)
__device__ inline float fexp2(float x) {
    float r; asm("v_exp_f32 %0, %1" : "=v"(r) : "v"(x)); return r;
}

// ---------------- kernel 1: per-channel partial sums ------------------------------
// 144 blocks x 64 rows (was 72x128): halves the serial row loop while KEEPING the
// x+y dual-stream MLP per block (R21's regression came from splitting the streams,
// not from block count). Deterministic: fixed partial layout, fixed order.
__global__ void stats_partial(const float* __restrict__ x,
                              const float* __restrict__ y,
                              float* __restrict__ part) {
    int c = threadIdx.x;                  // 256 threads = 256 channels
    int r0 = blockIdx.x * 64;             // 144 blocks * 64 rows = 9216
    float xs = 0.f, xq = 0.f, ys = 0.f, yq = 0.f;
    for (int r = r0; r < r0 + 64; ++r) {
        float xv = x[(size_t)r * CH + c]; xs += xv; xq += xv * xv;
        float yv = y[(size_t)r * CH + c]; ys += yv; yq += yv * yv;
    }
    float* p = part + (size_t)blockIdx.x * 1024;
    p[c] = xs; p[256 + c] = xq; p[512 + c] = ys; p[768 + c] = yq;
}

// ---------------- kernel 2: finalize stats — 4 blocks, 1 output/thread -------------
__global__ void stats_final(const float* __restrict__ part, float* __restrict__ stats) {
    int o = blockIdx.x * 256 + threadIdx.x;           // 0..1023
    float s = 0.f;
    for (int b = 0; b < 144; ++b) s += part[(size_t)b * 1024 + o];
    float v;
    if (o < 256)      v = s / (float)HW_N;            // x mean
    else if (o < 512) v = SCALE2 / sqrtf(s);          // x invnorm (logit scale folded)
    else if (o < 768) v = s / (float)HW_N;            // y mean
    else              v = 1.0f / sqrtf(s);            // y invnorm
    stats[o] = v;
}

// ---------------- kernel 3: normalize f32 -> bf16; y goes to PACKED layout ---------
// ynP element index: keyblk*4096 + kk*512 + l16*128 + l15*8 + j
// so that in attn, lane l = l16*16+l15 reads its B-fragment as bytes
// [l*16, l*16+16) of the contiguous 1KB segment (keyblk, kk): fully coalesced.
__global__ void normalize_k(const float* __restrict__ x,
                            const float* __restrict__ y,
                            const float* __restrict__ stats,
                            unsigned short* __restrict__ xn,
                            unsigned short* __restrict__ ynP) {
    int idx = (blockIdx.x * 256 + threadIdx.x) * 8;   // grid.x = 1152
    int c = idx & (CH - 1);
    const float* src = blockIdx.y ? y : x;
    const float* st = stats + blockIdx.y * 512;
    float4 v0 = *(const float4*)(src + idx);
    float4 v1 = *(const float4*)(src + idx + 4);
    float f[8] = {v0.x, v0.y, v0.z, v0.w, v1.x, v1.y, v1.z, v1.w};
    bf16x8 o;
#pragma unroll
    for (int j = 0; j < 8; ++j)
        o[j] = (short)f2b((f[j] - st[c + j]) * st[256 + c + j]);
    if (blockIdx.y == 0) {
        *(bf16x8*)(xn + idx) = o;                     // row-major for A-fragments
    } else {
        int key = idx >> 8;
        int dst = (key >> 4) * 4096 + (c >> 5) * 512 + ((c & 31) >> 3) * 128 + (key & 15) * 8;
        *(bf16x8*)(ynP + dst) = o;                    // packed B-fragment layout
    }
}

// ---------------- kernel 4: fused corr -> softmax -> PV (R20/R23 verbatim) ---------
// 72*nsplit blocks (XCD swizzle), 256 thr = 4 waves, wave owns 32 q-rows.
// Verified best: interleaved next-tile loads inside the MFMA sequence (b[kk]
// overwritten after its last use), no setprio, per-lane segbase addressing,
// block-uniform stagger. Closed branches (measured): occupancy >2 blk/CU spills
// (VGPR law 256/waves_per_eu); T15 deferred-softmax spills (R14/R22); tile
// stagger + s_sleep anti-phase null; 8 acc chains null; LDS+counted-vmcnt worse.
__launch_bounds__(256, 2)
__global__ void attn_k(const unsigned short* __restrict__ xn,
                       const unsigned short* __restrict__ ynP,
                       const float* __restrict__ refimg,
                       float* __restrict__ part, int nsplit) {
    int tid = threadIdx.x;
    int lane = tid & 63, wave = tid >> 6;
    int l15 = lane & 15, l16 = lane >> 4;

    // XCD-chunked bijective swizzle (grid % 8 == 0)
    int chunk = gridDim.x >> 3;
    int wg = (blockIdx.x & 7) * chunk + (blockIdx.x >> 3);
    int bx = wg % 72, by = wg / 72;
    int qb = bx * 128 + wave * 32;
    int keys_per_split = HW_N / nsplit;
    int key0 = by * keys_per_split;
    int ntile = keys_per_split / KBLK;
    int phase = (wg * 5) % ntile;                     // block-uniform stagger (proven text)

    // A fragments (xn pre-scaled by SCALE2): q = qb + qs*16 + l15, k = kk*32 + l16*8 + j
    bf16x8 a[2][8];
#pragma unroll
    for (int qs = 0; qs < 2; ++qs) {
        const unsigned short* xrow = xn + (size_t)(qb + qs * 16 + l15) * CH + l16 * 8;
#pragma unroll
        for (int kk = 0; kk < 8; ++kk) a[qs][kk] = *(const bf16x8*)(xrow + kk * 32);
    }

    // lane-local state: plain max + raw exp sums (logits bounded, no rescale needed)
    float M[2][4], den[2][4], nA[2][4], nB[2][4];
#pragma unroll
    for (int qs = 0; qs < 2; ++qs)
#pragma unroll
        for (int i = 0; i < 4; ++i) {
            M[qs][i] = -1e30f; den[qs][i] = 0.f; nA[qs][i] = 0.f; nB[qs][i] = 0.f;
        }

    const float* refA = refimg + HW_N;
    const float* refB = refimg + 2 * HW_N;
    // per-lane base into packed layout: lane*16 bytes within each 1KB (keyblk,kk) segment
    const char* segbase = (const char*)ynP + ((size_t)(key0 >> 4) << 13) + lane * 16;

    bf16x8 b0[8], b1[8];
    float va0, vb0, va1, vb1;

    // prologue: load tile `phase`
    int tc = phase;
    {
        const char* seg = segbase + ((size_t)tc << 14);
#pragma unroll
        for (int kk = 0; kk < 8; ++kk) {
            b0[kk] = *(const bf16x8*)(seg + kk * 1024);
            b1[kk] = *(const bf16x8*)(seg + 8192 + kk * 1024);
        }
        int kb = key0 + tc * KBLK;
        va0 = refA[kb + l15];      vb0 = refB[kb + l15];
        va1 = refA[kb + 16 + l15]; vb1 = refB[kb + 16 + l15];
    }

    // main loop: ntile-1 iterations, always loading the next tile inside the MFMAs
    for (int tt = 0; tt < ntile - 1; ++tt) {
        int tn = tc + 1; if (tn == ntile) tn = 0;
        const char* segn = segbase + ((size_t)tn << 14);

        f32x4 acc0[2], acc1[2];
#pragma unroll
        for (int ct = 0; ct < 2; ++ct) {
            acc0[ct] = (f32x4){0.f, 0.f, 0.f, 0.f};
            acc1[ct] = (f32x4){0.f, 0.f, 0.f, 0.f};
        }
#pragma unroll
        for (int kk = 0; kk < 8; ++kk) {
            acc0[0] = __builtin_amdgcn_mfma_f32_16x16x32_bf16(a[0][kk], b0[kk], acc0[0], 0, 0, 0);
            acc1[0] = __builtin_amdgcn_mfma_f32_16x16x32_bf16(a[1][kk], b0[kk], acc1[0], 0, 0, 0);
            acc0[1] = __builtin_amdgcn_mfma_f32_16x16x32_bf16(a[0][kk], b1[kk], acc0[1], 0, 0, 0);
            acc1[1] = __builtin_amdgcn_mfma_f32_16x16x32_bf16(a[1][kk], b1[kk], acc1[1], 0, 0, 0);
            // b0[kk]/b1[kk] now dead for this tile: overwrite with next tile's data
            b0[kk] = *(const bf16x8*)(segn + kk * 1024);
            b1[kk] = *(const bf16x8*)(segn + 8192 + kk * 1024);
        }

        // snapshot current colors, fetch next tile's colors
        float cva0 = va0, cvb0 = vb0, cva1 = va1, cvb1 = vb1;
        {
            int kb = key0 + tn * KBLK;
            va0 = refA[kb + l15];      vb0 = refB[kb + l15];
            va1 = refA[kb + 16 + l15]; vb1 = refB[kb + 16 + l15];
        }
        tc = tn;

        // softmax covers the in-flight loads.
#pragma unroll
        for (int qs = 0; qs < 2; ++qs)
#pragma unroll
            for (int i = 0; i < 4; ++i) {
                float c0 = qs ? acc1[0][i] : acc0[0][i];
                float c1 = qs ? acc1[1][i] : acc0[1][i];
                M[qs][i] = fmaxf(fmaxf(M[qs][i], c0), c1);
                float p0 = fexp2(c0);
                float p1 = fexp2(c1);
                den[qs][i] += p0 + p1;
                nA[qs][i] += p0 * cva0 + p1 * cva1;
                nB[qs][i] += p0 * cvb0 + p1 * cvb1;
            }
    }

    // final tile: MFMA + softmax, no loads
    {
        f32x4 acc0[2], acc1[2];
#pragma unroll
        for (int ct = 0; ct < 2; ++ct) {
            acc0[ct] = (f32x4){0.f, 0.f, 0.f, 0.f};
            acc1[ct] = (f32x4){0.f, 0.f, 0.f, 0.f};
        }
#pragma unroll
        for (int kk = 0; kk < 8; ++kk) {
            acc0[0] = __builtin_amdgcn_mfma_f32_16x16x32_bf16(a[0][kk], b0[kk], acc0[0], 0, 0, 0);
            acc1[0] = __builtin_amdgcn_mfma_f32_16x16x32_bf16(a[1][kk], b0[kk], acc1[0], 0, 0, 0);
            acc0[1] = __builtin_amdgcn_mfma_f32_16x16x32_bf16(a[0][kk], b1[kk], acc0[1], 0, 0, 0);
            acc1[1] = __builtin_amdgcn_mfma_f32_16x16x32_bf16(a[1][kk], b1[kk], acc1[1], 0, 0, 0);
        }
#pragma unroll
        for (int qs = 0; qs < 2; ++qs)
#pragma unroll
            for (int i = 0; i < 4; ++i) {
                float c0 = qs ? acc1[0][i] : acc0[0][i];
                float c1 = qs ? acc1[1][i] : acc0[1][i];
                M[qs][i] = fmaxf(fmaxf(M[qs][i], c0), c1);
                float p0 = fexp2(c0);
                float p1 = fexp2(c1);
                den[qs][i] += p0 + p1;
                nA[qs][i] += p0 * va0 + p1 * va1;
                nB[qs][i] += p0 * vb0 + p1 * vb1;
            }
    }

    // merge lane-local states across the 16 column-lanes: plain sum + max
#pragma unroll
    for (int qs = 0; qs < 2; ++qs)
#pragma unroll
        for (int i = 0; i < 4; ++i) {
#pragma unroll
            for (int off = 1; off < 16; off <<= 1) {
                M[qs][i]   = fmaxf(M[qs][i], __shfl_xor(M[qs][i], off, 64));
                den[qs][i] += __shfl_xor(den[qs][i], off, 64);
                nA[qs][i]  += __shfl_xor(nA[qs][i], off, 64);
                nB[qs][i]  += __shfl_xor(nB[qs][i], off, 64);
            }
        }
    if (l15 == 0) {
#pragma unroll
        for (int qs = 0; qs < 2; ++qs)
#pragma unroll
            for (int i = 0; i < 4; ++i) {
                int q = qb + qs * 16 + l16 * 4 + i;
                float* p = part + ((size_t)by * HW_N + q) * 4;
                p[0] = M[qs][i]; p[1] = den[qs][i]; p[2] = nA[qs][i]; p[3] = nB[qs][i];
            }
    }
}

// ---------------- kernel 5: merge splits, write f32 outputs ------------------------
__global__ void combine_k(const float* __restrict__ part, float* __restrict__ out,
                          int nsplit) {
    int q = blockIdx.x * 256 + threadIdx.x;           // 36 blocks
    float M = -1e30f, den = 0.f, nA = 0.f, nB = 0.f;
    for (int s = 0; s < nsplit; ++s) {
        const float* p = part + ((size_t)s * HW_N + q) * 4;
        M = fmaxf(M, p[0]); den += p[1]; nA += p[2]; nB += p[3];
    }
    out[q]            = nA / den;            // W channel a
    out[HW_N + q]     = nB / den;            // W channel b
    out[2 * HW_N + q] = M * INV_SCALE2;      // confidence = max corr (unscale)
}

extern "C" void kernel_launch(void* const* d_in, const int* in_sizes, int n_in,
                              void* d_out, int out_size, void* d_ws, size_t ws_size,
                              hipStream_t stream) {
    (void)in_sizes; (void)n_in; (void)out_size;
    const float* x   = (const float*)d_in[0];
    const float* y   = (const float*)d_in[1];
    const float* ref = (const float*)d_in[2];
    float* out = (float*)d_out;

    char* ws = (char*)d_ws;
    unsigned short* xn  = (unsigned short*)ws;                    // 4718592 B
    unsigned short* ynP = (unsigned short*)(ws + 4718592);        // 4718592 B (packed)
    float* partA = (float*)ws;                                    // 589824 B (dead before xn written)
    float* stats = (float*)(ws + 2 * 4718592);                    // 4096 B
    float* partS = (float*)(ws + 2 * 4718592 + 4096);             // nsplit*9216*16 B

    size_t base = 2 * 4718592 + 4096;
    int nsplit = (ws_size >= base + (size_t)12 * HW_N * 16) ? 12 : 6;

    hipLaunchKernelGGL(stats_partial, dim3(144), dim3(256), 0, stream, x, y, partA);
    hipLaunchKernelGGL(stats_final, dim3(4), dim3(256), 0, stream, partA, stats);
    hipLaunchKernelGGL(normalize_k, dim3(1152, 2), dim3(256), 0, stream, x, y, stats, xn, ynP);
    hipLaunchKernelGGL(attn_k, dim3(72 * nsplit), dim3(256), 0, stream, xn, ynP, ref, partS, nsplit);
    hipLaunchKernelGGL(combine_k, dim3(36), dim3(256), 0, stream, partS, out, nsplit);
}